// Round 3
// baseline (217.690 us; speedup 1.0000x reference)
//
#include <hip/hip_runtime.h>

#define NPART 4096
#define NBATCH 2
#define MAXC 128

// ---------------------------------------------------------------------------
// Kernel 1: per-batch min/max over locs -> grid lower bound + integer dims.
// f32 arithmetic, op-for-op with the reference (verified: output 0 passes).
// ---------------------------------------------------------------------------
__global__ __launch_bounds__(256) void bounds_kernel(
    const float* __restrict__ locs, float* __restrict__ lower2,
    int* __restrict__ gdi) {
  int b = blockIdx.x;
  int tid = threadIdx.x;
  __shared__ float smn[3][256];
  __shared__ float smx[3][256];
  float mn0 = 1e30f, mn1 = 1e30f, mn2 = 1e30f;
  float mx0 = -1e30f, mx1 = -1e30f, mx2 = -1e30f;
  const float* base = locs + (size_t)b * NPART * 3;
  for (int n = tid; n < NPART; n += 256) {
    float x = base[n * 3 + 0];
    float y = base[n * 3 + 1];
    float z = base[n * 3 + 2];
    mn0 = fminf(mn0, x); mx0 = fmaxf(mx0, x);
    mn1 = fminf(mn1, y); mx1 = fmaxf(mx1, y);
    mn2 = fminf(mn2, z); mx2 = fmaxf(mx2, z);
  }
  smn[0][tid] = mn0; smn[1][tid] = mn1; smn[2][tid] = mn2;
  smx[0][tid] = mx0; smx[1][tid] = mx1; smx[2][tid] = mx2;
  __syncthreads();
  for (int s = 128; s > 0; s >>= 1) {
    if (tid < s) {
      for (int d = 0; d < 3; d++) {
        smn[d][tid] = fminf(smn[d][tid], smn[d][tid + s]);
        smx[d][tid] = fmaxf(smx[d][tid], smx[d][tid + s]);
      }
    }
    __syncthreads();
  }
  if (tid == 0) {
    for (int d = 0; d < 3; d++) {
      float lo = smn[d][0];
      float up = smx[d][0];
      float t = (up - lo) / 0.1f;                 // fp32 IEEE div
      t = fminf(fmaxf(t, 0.0f), 96.0f);           // clip(.., 0, MAX_GRID_DIM)
      float gdim = ceilf(t);
      float ctr = (lo + up) * 0.5f;
      float l2 = ctr - ((gdim * 0.1f) * 0.5f);    // center - grid_dims*R*0.5
      float g = fmaxf(gdim, 1.0f);
      lower2[b * 3 + d] = l2;
      gdi[b * 3 + d] = (int)g;
    }
  }
}

// ---------------------------------------------------------------------------
// Kernel 2: per-particle cell id (row-major over grid dims), f32 math.
// ---------------------------------------------------------------------------
__global__ __launch_bounds__(256) void cellid_kernel(
    const float* __restrict__ locs, const float* __restrict__ lower2,
    const int* __restrict__ gdi, int* __restrict__ cell_ids) {
  int i = blockIdx.x * 256 + threadIdx.x;  // [0, NBATCH*NPART)
  if (i >= NBATCH * NPART) return;
  int b = i >> 12;
  int c[3];
  for (int d = 0; d < 3; d++) {
    float v = locs[(size_t)i * 3 + d];
    float cf = floorf((v - lower2[b * 3 + d]) / 0.1f);
    float gdf = (float)gdi[b * 3 + d];
    cf = fminf(fmaxf(cf, 0.0f), gdf - 1.0f);
    c[d] = (int)cf;
  }
  cell_ids[i] = (c[0] * gdi[b * 3 + 1] + c[1]) * gdi[b * 3 + 2] + c[2];
}

// ---------------------------------------------------------------------------
// Kernel 3: stable rank sort. rank_i = #{j : c_j < c_i or (c_j==c_i and j<i)}.
// Scatter order[rank]=i and idxs output. Grid: 16 blocks per batch.
// ---------------------------------------------------------------------------
__global__ __launch_bounds__(256) void rank_kernel(
    const int* __restrict__ cell_ids, int* __restrict__ order,
    float* __restrict__ out_idxs) {
  int b = blockIdx.x >> 4;
  int base = (blockIdx.x & 15) << 8;
  __shared__ int sc[NPART];
  for (int j = threadIdx.x; j < NPART; j += 256) sc[j] = cell_ids[b * NPART + j];
  __syncthreads();
  int i = base + threadIdx.x;
  int ci = sc[i];
  int cnt = 0;
  for (int j = 0; j < NPART; j++) {
    int cj = sc[j];
    cnt += (cj < ci) || (cj == ci && j < i);
  }
  order[b * NPART + cnt] = i;
  out_idxs[b * NPART + cnt] = (float)i;
}

// ---------------------------------------------------------------------------
// Kernel 4: gather sorted locs/data; emit locs_s and data_s outputs, plus
// float4 (x,y,z,sq) workspace for the neighbor kernel.
// sq = (x*x + y*y) + z*z with explicit rn mul/add — matches numpy's
// (l*l).sum(-1): products materialized first, so NO fma here.
// ---------------------------------------------------------------------------
__global__ __launch_bounds__(256) void gather_kernel(
    const float* __restrict__ locs, const float* __restrict__ data,
    const int* __restrict__ order, float4* __restrict__ slocs,
    float* __restrict__ out_locs, float* __restrict__ out_data) {
  int p = blockIdx.x * 256 + threadIdx.x;  // [0, NBATCH*NPART)
  if (p >= NBATCH * NPART) return;
  int b = p >> 12;
  int i = order[p];
  size_t src = (size_t)b * NPART + i;
  float x = locs[src * 3 + 0];
  float y = locs[src * 3 + 1];
  float z = locs[src * 3 + 2];
  float sq = __fadd_rn(__fadd_rn(__fmul_rn(x, x), __fmul_rn(y, y)),
                       __fmul_rn(z, z));
  out_locs[(size_t)p * 3 + 0] = x;
  out_locs[(size_t)p * 3 + 1] = y;
  out_locs[(size_t)p * 3 + 2] = z;
  slocs[p] = make_float4(x, y, z, sq);
  const float* dsrc = data + src * 16;
  float* ddst = out_data + (size_t)p * 16;
  for (int k = 0; k < 16; k++) ddst[k] = dsrc[k];
}

// ---------------------------------------------------------------------------
// Kernel 5: neighbor lists. One wave per sorted particle n; batch's sorted
// locs+sq staged in 64KB LDS.
//   dot = fma(z·z', fma(y·y', rn(x·x')))   <- BLAS/contracted einsum schedule
//   d2  = rn(sq_n + sq_m) - rn(2·dot)      <- separate ufuncs, rn
//   hit = d2 <= 0.01f
// Ordered append via ballot + prefix popcount; -1 padding to MAXC.
// ---------------------------------------------------------------------------
__global__ __launch_bounds__(256) void nbr_kernel(
    const float4* __restrict__ slocs, float* __restrict__ out_nbr) {
  int b = blockIdx.y;
  __shared__ float4 sl[NPART];  // 64 KB
  for (int j = threadIdx.x; j < NPART; j += 256) sl[j] = slocs[b * NPART + j];
  __syncthreads();
  int wave = threadIdx.x >> 6;
  int lane = threadIdx.x & 63;
  int n = blockIdx.x * 4 + wave;
  float4 me = sl[n];
  float* row = out_nbr + ((size_t)b * NPART + n) * MAXC;
  int count = 0;
  for (int base2 = 0; base2 < NPART; base2 += 64) {
    int m = base2 + lane;
    float4 o = sl[m];
    float dot = __fmaf_rn(me.z, o.z,
                 __fmaf_rn(me.y, o.y, __fmul_rn(me.x, o.x)));
    float d2 = __fsub_rn(__fadd_rn(me.w, o.w), __fmul_rn(2.0f, dot));
    bool hit = d2 <= 0.01f;
    unsigned long long bal = __ballot(hit);
    int pre = __popcll(bal & ((1ull << lane) - 1ull));
    int pos = count + pre;
    if (hit && pos < MAXC) row[pos] = (float)m;
    count += __popcll(bal);
    if (count >= MAXC) break;
  }
  for (int p = min(count, MAXC) + lane; p < MAXC; p += 64) row[p] = -1.0f;
}

// ---------------------------------------------------------------------------
extern "C" void kernel_launch(void* const* d_in, const int* in_sizes, int n_in,
                              void* d_out, int out_size, void* d_ws,
                              size_t ws_size, hipStream_t stream) {
  const float* locs = (const float*)d_in[0];  // [2,4096,3]
  const float* data = (const float*)d_in[1];  // [2,4096,16]

  float* out = (float*)d_out;
  float* out_idxs = out;                                  // [2,4096]
  float* out_nbr = out + NBATCH * NPART;                  // [2,4096,128]
  float* out_locs = out_nbr + (size_t)NBATCH * NPART * MAXC;  // [2,4096,3]
  float* out_data = out_locs + (size_t)NBATCH * NPART * 3;    // [2,4096,16]

  // Workspace layout (bytes): lower2 fp32[6] @0, gdi int[6] @32,
  // cell_ids int[8192] @64, order int[8192] @32832, slocs float4[8192] @65600.
  float* lower2 = (float*)d_ws;
  int* gdi = (int*)((char*)d_ws + 32);
  int* cell_ids = (int*)((char*)d_ws + 64);
  int* order = (int*)((char*)d_ws + 64 + NBATCH * NPART * 4);
  float4* slocs = (float4*)((char*)d_ws + 64 + 2 * NBATCH * NPART * 4);

  bounds_kernel<<<NBATCH, 256, 0, stream>>>(locs, lower2, gdi);
  cellid_kernel<<<(NBATCH * NPART + 255) / 256, 256, 0, stream>>>(
      locs, lower2, gdi, cell_ids);
  rank_kernel<<<NBATCH * 16, 256, 0, stream>>>(cell_ids, order, out_idxs);
  gather_kernel<<<(NBATCH * NPART + 255) / 256, 256, 0, stream>>>(
      locs, data, order, slocs, out_locs, out_data);
  nbr_kernel<<<dim3(NPART / 4, NBATCH), 256, 0, stream>>>(slocs, out_nbr);
}

// Round 4
// 126.363 us; speedup vs baseline: 1.7227x; 1.7227x over previous
//
#include <hip/hip_runtime.h>

#define NPART 4096
#define NBATCH 2
#define MAXC 128

// ---------------------------------------------------------------------------
// Kernel 1: per-batch min/max over locs -> grid lower bound + integer dims.
// Also zeroes the rank-counter buffer (ws is re-poisoned before every call).
// f32 arithmetic, op-for-op with the reference (verified bit-exact).
// ---------------------------------------------------------------------------
__global__ __launch_bounds__(256) void bounds_kernel(
    const float* __restrict__ locs, float* __restrict__ lower2,
    int* __restrict__ gdi, int* __restrict__ rank) {
  int b = blockIdx.x;
  int tid = threadIdx.x;
  // zero this batch's rank counters
  for (int n = tid; n < NPART; n += 256) rank[b * NPART + n] = 0;
  __shared__ float smn[3][256];
  __shared__ float smx[3][256];
  float mn0 = 1e30f, mn1 = 1e30f, mn2 = 1e30f;
  float mx0 = -1e30f, mx1 = -1e30f, mx2 = -1e30f;
  const float* base = locs + (size_t)b * NPART * 3;
  for (int n = tid; n < NPART; n += 256) {
    float x = base[n * 3 + 0];
    float y = base[n * 3 + 1];
    float z = base[n * 3 + 2];
    mn0 = fminf(mn0, x); mx0 = fmaxf(mx0, x);
    mn1 = fminf(mn1, y); mx1 = fmaxf(mx1, y);
    mn2 = fminf(mn2, z); mx2 = fmaxf(mx2, z);
  }
  smn[0][tid] = mn0; smn[1][tid] = mn1; smn[2][tid] = mn2;
  smx[0][tid] = mx0; smx[1][tid] = mx1; smx[2][tid] = mx2;
  __syncthreads();
  for (int s = 128; s > 0; s >>= 1) {
    if (tid < s) {
      for (int d = 0; d < 3; d++) {
        smn[d][tid] = fminf(smn[d][tid], smn[d][tid + s]);
        smx[d][tid] = fmaxf(smx[d][tid], smx[d][tid + s]);
      }
    }
    __syncthreads();
  }
  if (tid == 0) {
    for (int d = 0; d < 3; d++) {
      float lo = smn[d][0];
      float up = smx[d][0];
      float t = (up - lo) / 0.1f;                 // fp32 IEEE div
      t = fminf(fmaxf(t, 0.0f), 96.0f);           // clip(.., 0, MAX_GRID_DIM)
      float gdim = ceilf(t);
      float ctr = (lo + up) * 0.5f;
      float l2 = ctr - ((gdim * 0.1f) * 0.5f);    // center - grid_dims*R*0.5
      float g = fmaxf(gdim, 1.0f);
      lower2[b * 3 + d] = l2;
      gdi[b * 3 + d] = (int)g;
    }
  }
}

// ---------------------------------------------------------------------------
// Kernel 2: per-particle cell id (row-major over grid dims), f32 math.
// ---------------------------------------------------------------------------
__global__ __launch_bounds__(256) void cellid_kernel(
    const float* __restrict__ locs, const float* __restrict__ lower2,
    const int* __restrict__ gdi, int* __restrict__ cell_ids) {
  int i = blockIdx.x * 256 + threadIdx.x;  // [0, NBATCH*NPART)
  if (i >= NBATCH * NPART) return;
  int b = i >> 12;
  int c[3];
  for (int d = 0; d < 3; d++) {
    float v = locs[(size_t)i * 3 + d];
    float cf = floorf((v - lower2[b * 3 + d]) / 0.1f);
    float gdf = (float)gdi[b * 3 + d];
    cf = fminf(fmaxf(cf, 0.0f), gdf - 1.0f);
    c[d] = (int)cf;
  }
  cell_ids[i] = (c[0] * gdi[b * 3 + 1] + c[1]) * gdi[b * 3 + 2] + c[2];
}

// ---------------------------------------------------------------------------
// Kernel 3a: partial stable-rank counts, j-chunked for full-GPU parallelism.
// Grid: NBATCH*16*16 = 512 blocks. Block (b, ic, jc): threads own
// i = ic*256+tid, scan the 256-wide j-chunk staged in LDS (broadcast reads).
// rank_i = #{j : c_j < c_i or (c_j==c_i and j<i)}; integer atomics are
// associative -> deterministic.
// ---------------------------------------------------------------------------
__global__ __launch_bounds__(256) void rank_part_kernel(
    const int* __restrict__ cell_ids, int* __restrict__ rank) {
  int bx = blockIdx.x;
  int b = bx >> 8;
  int ic = (bx >> 4) & 15;
  int jc = bx & 15;
  int tid = threadIdx.x;
  __shared__ int scj[256];
  scj[tid] = cell_ids[b * NPART + jc * 256 + tid];
  int ci = cell_ids[b * NPART + ic * 256 + tid];
  __syncthreads();
  int cnt = 0;
  if (jc < ic) {
#pragma unroll 8
    for (int j = 0; j < 256; j++) cnt += (scj[j] <= ci);
  } else if (jc > ic) {
#pragma unroll 8
    for (int j = 0; j < 256; j++) cnt += (scj[j] < ci);
  } else {
#pragma unroll 8
    for (int j = 0; j < 256; j++) {
      int cj = scj[j];
      cnt += (cj < ci) || (cj == ci && j < tid);
    }
  }
  atomicAdd(&rank[b * NPART + ic * 256 + tid], cnt);
}

// ---------------------------------------------------------------------------
// Kernel 3b: scatter order + idxs from final ranks.
// ---------------------------------------------------------------------------
__global__ __launch_bounds__(256) void rank_scatter_kernel(
    const int* __restrict__ rank, int* __restrict__ order,
    float* __restrict__ out_idxs) {
  int p = blockIdx.x * 256 + threadIdx.x;  // [0, NBATCH*NPART)
  if (p >= NBATCH * NPART) return;
  int b = p >> 12;
  int i = p & (NPART - 1);
  int r = rank[p];
  order[b * NPART + r] = i;
  out_idxs[b * NPART + r] = (float)i;
}

// ---------------------------------------------------------------------------
// Kernel 4: gather sorted locs/data; emit locs_s and data_s outputs, plus
// float4 (x,y,z,sq) workspace for the neighbor kernel.
// sq = (x*x + y*y) + z*z with explicit rn mul/add (numpy: products
// materialized by l*l, then sum -> NO fma here).
// ---------------------------------------------------------------------------
__global__ __launch_bounds__(256) void gather_kernel(
    const float* __restrict__ locs, const float* __restrict__ data,
    const int* __restrict__ order, float4* __restrict__ slocs,
    float* __restrict__ out_locs, float* __restrict__ out_data) {
  int p = blockIdx.x * 256 + threadIdx.x;  // [0, NBATCH*NPART)
  if (p >= NBATCH * NPART) return;
  int b = p >> 12;
  int i = order[p];
  size_t src = (size_t)b * NPART + i;
  float x = locs[src * 3 + 0];
  float y = locs[src * 3 + 1];
  float z = locs[src * 3 + 2];
  float sq = __fadd_rn(__fadd_rn(__fmul_rn(x, x), __fmul_rn(y, y)),
                       __fmul_rn(z, z));
  out_locs[(size_t)p * 3 + 0] = x;
  out_locs[(size_t)p * 3 + 1] = y;
  out_locs[(size_t)p * 3 + 2] = z;
  slocs[p] = make_float4(x, y, z, sq);
  const float* dsrc = data + src * 16;
  float* ddst = out_data + (size_t)p * 16;
  for (int k = 0; k < 16; k++) ddst[k] = dsrc[k];
}

// ---------------------------------------------------------------------------
// Kernel 5: neighbor lists. One wave per sorted particle n; batch's sorted
// locs+sq staged in 64KB LDS.
//   dot = fma(z·z', fma(y·y', rn(x·x')))   <- BLAS/contracted einsum schedule
//   d2  = rn(sq_n + sq_m) - rn(2·dot)      <- separate ufuncs, rn
//   hit = d2 <= 0.01f                       (verified bit-exact vs ref)
// Ordered append via ballot + prefix popcount; -1 padding to MAXC.
// ---------------------------------------------------------------------------
__global__ __launch_bounds__(256) void nbr_kernel(
    const float4* __restrict__ slocs, float* __restrict__ out_nbr) {
  int b = blockIdx.y;
  __shared__ float4 sl[NPART];  // 64 KB
  for (int j = threadIdx.x; j < NPART; j += 256) sl[j] = slocs[b * NPART + j];
  __syncthreads();
  int wave = threadIdx.x >> 6;
  int lane = threadIdx.x & 63;
  int n = blockIdx.x * 4 + wave;
  float4 me = sl[n];
  float* row = out_nbr + ((size_t)b * NPART + n) * MAXC;
  int count = 0;
  for (int base2 = 0; base2 < NPART; base2 += 64) {
    int m = base2 + lane;
    float4 o = sl[m];
    float dot = __fmaf_rn(me.z, o.z,
                 __fmaf_rn(me.y, o.y, __fmul_rn(me.x, o.x)));
    float d2 = __fsub_rn(__fadd_rn(me.w, o.w), __fmul_rn(2.0f, dot));
    bool hit = d2 <= 0.01f;
    unsigned long long bal = __ballot(hit);
    int pre = __popcll(bal & ((1ull << lane) - 1ull));
    int pos = count + pre;
    if (hit && pos < MAXC) row[pos] = (float)m;
    count += __popcll(bal);
    if (count >= MAXC) break;
  }
  for (int p = min(count, MAXC) + lane; p < MAXC; p += 64) row[p] = -1.0f;
}

// ---------------------------------------------------------------------------
extern "C" void kernel_launch(void* const* d_in, const int* in_sizes, int n_in,
                              void* d_out, int out_size, void* d_ws,
                              size_t ws_size, hipStream_t stream) {
  const float* locs = (const float*)d_in[0];  // [2,4096,3]
  const float* data = (const float*)d_in[1];  // [2,4096,16]

  float* out = (float*)d_out;
  float* out_idxs = out;                                  // [2,4096]
  float* out_nbr = out + NBATCH * NPART;                  // [2,4096,128]
  float* out_locs = out_nbr + (size_t)NBATCH * NPART * MAXC;  // [2,4096,3]
  float* out_data = out_locs + (size_t)NBATCH * NPART * 3;    // [2,4096,16]

  // Workspace layout (bytes):
  //   lower2 f32[6]   @ 0
  //   gdi    i32[6]   @ 32
  //   cell_ids i32[8192] @ 64       (ends 32832)
  //   order    i32[8192] @ 32832    (ends 65600)
  //   rank     i32[8192] @ 65600    (ends 98368)
  //   slocs  float4[8192] @ 98368   (16B aligned; ends 229440)
  float* lower2 = (float*)d_ws;
  int* gdi = (int*)((char*)d_ws + 32);
  int* cell_ids = (int*)((char*)d_ws + 64);
  int* order = (int*)((char*)d_ws + 64 + NBATCH * NPART * 4);
  int* rank = (int*)((char*)d_ws + 64 + 2 * NBATCH * NPART * 4);
  float4* slocs = (float4*)((char*)d_ws + 64 + 3 * NBATCH * NPART * 4);

  bounds_kernel<<<NBATCH, 256, 0, stream>>>(locs, lower2, gdi, rank);
  cellid_kernel<<<(NBATCH * NPART + 255) / 256, 256, 0, stream>>>(
      locs, lower2, gdi, cell_ids);
  rank_part_kernel<<<NBATCH * 256, 256, 0, stream>>>(cell_ids, rank);
  rank_scatter_kernel<<<(NBATCH * NPART + 255) / 256, 256, 0, stream>>>(
      rank, order, out_idxs);
  gather_kernel<<<(NBATCH * NPART + 255) / 256, 256, 0, stream>>>(
      locs, data, order, slocs, out_locs, out_data);
  nbr_kernel<<<dim3(NPART / 4, NBATCH), 256, 0, stream>>>(slocs, out_nbr);
}